// Round 4
// baseline (10338.962 us; speedup 1.0000x reference)
//
#include <hip/hip_runtime.h>
#include <hip/hip_bf16.h>
#include <math.h>

#define B_  2048
#define S_  128
#define H_  512
#define K_  16
#define NSTEP 63

typedef __bf16 bf16x8 __attribute__((ext_vector_type(8)));
typedef float  f32x4  __attribute__((ext_vector_type(4)));
typedef unsigned short u16x8 __attribute__((ext_vector_type(8)));

static __device__ __forceinline__ void f2b2(float v, unsigned short& hi, unsigned short& lo)
{
    __hip_bfloat16 h = __float2bfloat16(v);
    float r = v - __bfloat162float(h);
    __hip_bfloat16 l = __float2bfloat16(r);
    hi = __builtin_bit_cast(unsigned short, h);
    lo = __builtin_bit_cast(unsigned short, l);
}

static __device__ __forceinline__ void gl16(const unsigned short* g, unsigned short* l)
{
    __builtin_amdgcn_global_load_lds(
        (const __attribute__((address_space(1))) unsigned int*)g,
        (__attribute__((address_space(3))) unsigned int*)l, 16, 0, 0);
}

// ---- tiled core: BN=128 fixed, BM in {64,128}, BK=64, 256 thr = 4 waves (2x2), WN=64, WM=BM/2.
// LDS buffer: [Ah | Al | Bh | Bl]; plane chunked 16B; A chunk c = (row=c%BM, kgrp=c/BM).

template<int BM>
static __device__ __forceinline__ void stage_tile(
    const unsigned short* __restrict__ Ahi, const unsigned short* __restrict__ Alo, int lda,
    const unsigned short* __restrict__ Whi, const unsigned short* __restrict__ Wlo, int K,
    int rowBase, int colBase, int k0, unsigned short* buf, int tid)
{
    constexpr int PLA = BM*64, PLB = 128*64;
    unsigned short* Ah = buf;
    unsigned short* Al = buf + PLA;
    unsigned short* Bh = buf + 2*PLA;
    unsigned short* Bl = buf + 2*PLA + PLB;
    const int ub = tid & ~63;
#pragma unroll
    for (int c0 = 0; c0 < BM*8; c0 += 256) {
        int c = c0 + tid;
        int row = c % BM, g = c / BM;
        size_t off = (size_t)(rowBase + row) * lda + k0 + g*8;
        gl16(Ahi + off, Ah + (size_t)(c0 + ub)*8);
        gl16(Alo + off, Al + (size_t)(c0 + ub)*8);
    }
#pragma unroll
    for (int c0 = 0; c0 < 1024; c0 += 256) {
        int c = c0 + tid;
        int row = c & 127, g = c >> 7;
        size_t off = (size_t)(colBase + row) * K + k0 + g*8;
        gl16(Whi + off, Bh + (size_t)(c0 + ub)*8);
        gl16(Wlo + off, Bl + (size_t)(c0 + ub)*8);
    }
}

template<int BM>
static __device__ __forceinline__ void read_frags(
    const unsigned short* buf, int kk, int wr, int wc, int r16, int kg,
    bf16x8 (&a_h)[BM/32], bf16x8 (&a_l)[BM/32], bf16x8 (&b_h)[4], bf16x8 (&b_l)[4])
{
    constexpr int MI = BM/32;
    constexpr int PLA = BM*64, PLB = 128*64;
    const unsigned short* Ah = buf;
    const unsigned short* Al = buf + PLA;
    const unsigned short* Bh = buf + 2*PLA;
    const unsigned short* Bl = buf + 2*PLA + PLB;
#pragma unroll
    for (int i = 0; i < MI; ++i) {
        int ch = (kk*4 + kg)*BM + wr*(BM/2) + i*16 + r16;
        a_h[i] = __builtin_bit_cast(bf16x8, *(const u16x8*)(Ah + (size_t)ch*8));
        a_l[i] = __builtin_bit_cast(bf16x8, *(const u16x8*)(Al + (size_t)ch*8));
    }
#pragma unroll
    for (int j = 0; j < 4; ++j) {
        int ch = (kk*4 + kg)*128 + wc*64 + j*16 + r16;
        b_h[j] = __builtin_bit_cast(bf16x8, *(const u16x8*)(Bh + (size_t)ch*8));
        b_l[j] = __builtin_bit_cast(bf16x8, *(const u16x8*)(Bl + (size_t)ch*8));
    }
}

template<int MI>
static __device__ __forceinline__ void do_mfma(
    const bf16x8 (&a_h)[MI], const bf16x8 (&a_l)[MI],
    const bf16x8 (&b_h)[4], const bf16x8 (&b_l)[4], f32x4 (&acc)[MI][4])
{
#pragma unroll
    for (int i = 0; i < MI; ++i)
#pragma unroll
        for (int j = 0; j < 4; ++j) {
            acc[i][j] = __builtin_amdgcn_mfma_f32_16x16x32_bf16(a_h[i], b_h[j], acc[i][j], 0, 0, 0);
            acc[i][j] = __builtin_amdgcn_mfma_f32_16x16x32_bf16(a_h[i], b_l[j], acc[i][j], 0, 0, 0);
            acc[i][j] = __builtin_amdgcn_mfma_f32_16x16x32_bf16(a_l[i], b_h[j], acc[i][j], 0, 0, 0);
        }
}

template<int BM>
static __device__ __forceinline__ void gemm_core(
    unsigned short* lds,
    const unsigned short* __restrict__ Ahi, const unsigned short* __restrict__ Alo, int lda,
    const unsigned short* __restrict__ Whi, const unsigned short* __restrict__ Wlo, int K,
    int rowBase, int colBase, f32x4 (&acc)[BM/32][4])
{
    constexpr int MI = BM/32;
    constexpr int BUFSZ = 2*BM*64 + 2*128*64;
    const int tid = threadIdx.x, lane = tid & 63;
    const int wid = tid >> 6, wr = wid >> 1, wc = wid & 1;
    const int r16 = lane & 15, kg = lane >> 4;

    const int nt = K >> 6;
    stage_tile<BM>(Ahi, Alo, lda, Whi, Wlo, K, rowBase, colBase, 0, lds, tid);
    __syncthreads();

    for (int t = 0; t < nt; ++t) {
        unsigned short* cur = lds + (size_t)(t & 1) * BUFSZ;
        bf16x8 a_h[MI], a_l[MI], b_h[4], b_l[4];
        read_frags<BM>(cur, 0, wr, wc, r16, kg, a_h, a_l, b_h, b_l);
        if (t + 1 < nt)
            stage_tile<BM>(Ahi, Alo, lda, Whi, Wlo, K, rowBase, colBase, (t+1) << 6,
                           lds + (size_t)((t+1) & 1) * BUFSZ, tid);
        do_mfma<MI>(a_h, a_l, b_h, b_l, acc);
        read_frags<BM>(cur, 1, wr, wc, r16, kg, a_h, a_l, b_h, b_l);
        do_mfma<MI>(a_h, a_l, b_h, b_l, acc);
        __syncthreads();
    }
}

// ---------- phase kernels ----------
// C/D frag: col = lane&15, row = (lane>>4)*4 + reg.
// Swizzle: lid = (bid%8)*(G/8)+bid/8; strip = lid/RB; row = lid%RB (col-major per XCD chunk).

__global__ __launch_bounds__(256,1) void k1_phase(
    const unsigned short* __restrict__ ycH, const unsigned short* __restrict__ ycL,
    const unsigned short* __restrict__ w1tH, const unsigned short* __restrict__ w1tL,
    const float* __restrict__ g_w1, const float* __restrict__ f_w1,
    const float* __restrict__ g_b1, const float* __restrict__ f_b1,
    const float* __restrict__ ts, int step,
    unsigned short* __restrict__ HAh, unsigned short* __restrict__ HAl)
{
    constexpr int BM=64, MI=2;
    __shared__ __align__(16) unsigned short lds[2*(2*BM*64 + 2*128*64)];
    const int bid = blockIdx.x;
    const int lid = (bid & 7)*32 + (bid >> 3);
    const int strip = lid >> 5, rowb = lid & 31;
    const int rowBase = rowb*BM, colBase = strip*128;

    f32x4 acc[MI][4] = {};
    gemm_core<BM>(lds, ycH, ycL, S_, w1tH, w1tL, S_, rowBase, colBase, acc);

    const int tid=threadIdx.x, l=tid&63, wid=tid>>6;
    const int wr=wid>>1, wc=wid&1, r16=l&15, rg=l>>4;
    const float t = ts[3+step];
#pragma unroll
    for (int j=0;j<4;++j){
        int colj = colBase + wc*64 + j*16 + r16;
        float be = (colj < 512) ? (g_b1[colj] + t*g_w1[colj])
                                : (f_b1[colj-512] + t*f_w1[colj-512]);
#pragma unroll
        for (int i=0;i<MI;++i)
#pragma unroll
            for (int reg=0;reg<4;++reg){
                int row = rowBase + wr*(BM/2) + i*16 + rg*4 + reg;
                float v = fmaxf(acc[i][j][reg] + be, 0.f);
                unsigned short h,lo; f2b2(v,h,lo);
                size_t o = (size_t)row*1024 + colj;
                HAh[o]=h; HAl[o]=lo;
            }
    }
}

__global__ __launch_bounds__(256,1) void k2_phase(
    const unsigned short* __restrict__ HAh, const unsigned short* __restrict__ HAl,
    const unsigned short* __restrict__ gw2H, const unsigned short* __restrict__ gw2L,
    const unsigned short* __restrict__ fw2H, const unsigned short* __restrict__ fw2L,
    const float* __restrict__ g_b2, const float* __restrict__ f_b2,
    const float* __restrict__ y,
    const float* __restrict__ dWs,
    const float* __restrict__ ts, int step,
    float* __restrict__ gp,
    unsigned short* __restrict__ ytH, unsigned short* __restrict__ ytL,
    unsigned short* __restrict__ HBh, unsigned short* __restrict__ HBl)
{
    constexpr int BM=128, MI=4;
    __shared__ __align__(16) unsigned short lds[2*(2*BM*64 + 2*128*64)];
    const int bid = blockIdx.x;
    const int lid = (bid & 7)*40 + (bid >> 3);
    const int strip = lid >> 4, rowb = lid & 15;
    const int rowBase = rowb*BM;

    const int tid=threadIdx.x, l=tid&63, wid=tid>>6;
    const int wr=wid>>1, wc=wid&1, r16=l&15, rg=l>>4;

    f32x4 acc[MI][4] = {};
    if (strip < 16) {
        const int colBase = strip*128;
        gemm_core<BM>(lds, HAh, HAl, 1024, gw2H, gw2L, H_, rowBase, colBase, acc);
        const float dt = ts[4+step]-ts[3+step], sq = sqrtf(dt);
#pragma unroll
        for (int i=0;i<MI;++i)
#pragma unroll
            for (int reg=0;reg<4;++reg){
                int row = rowBase + wr*(BM/2) + i*16 + rg*4 + reg;
                float dwv = dWs[row*K_ + r16] * sq;
#pragma unroll
                for (int j=0;j<4;++j){
                    int colj = colBase + wc*64 + j*16;
                    float m = (acc[i][j][reg] + g_b2[colj + r16]) * dwv;
                    m += __shfl_xor(m,1); m += __shfl_xor(m,2);
                    m += __shfl_xor(m,4); m += __shfl_xor(m,8);
                    if (r16 == 0){
                        int idx = row*S_ + (colj>>4);
                        gp[idx] = m;
                        unsigned short h,lo; f2b2(y[idx] + m, h, lo);
                        ytH[idx]=h; ytL[idx]=lo;
                    }
                }
            }
    } else {
        const int colBase = (strip-16)*128;
        gemm_core<BM>(lds, HAh + 512, HAl + 512, 1024, fw2H, fw2L, H_, rowBase, colBase, acc);
#pragma unroll
        for (int j=0;j<4;++j){
            int colj = colBase + wc*64 + j*16 + r16;
            float be = f_b2[colj];
#pragma unroll
            for (int i=0;i<MI;++i)
#pragma unroll
                for (int reg=0;reg<4;++reg){
                    int row = rowBase + wr*(BM/2) + i*16 + rg*4 + reg;
                    float v = fmaxf(acc[i][j][reg] + be, 0.f);
                    unsigned short h,lo; f2b2(v,h,lo);
                    size_t o = (size_t)row*512 + colj;
                    HBh[o]=h; HBl[o]=lo;
                }
        }
    }
}

__global__ __launch_bounds__(256,1) void k3_phase(
    const unsigned short* __restrict__ ytH, const unsigned short* __restrict__ ytL,
    const unsigned short* __restrict__ w1tH, const unsigned short* __restrict__ w1tL,
    const float* __restrict__ g_b1, const float* __restrict__ g_w1,
    const unsigned short* __restrict__ HBh, const unsigned short* __restrict__ HBl,
    const unsigned short* __restrict__ fw3H, const unsigned short* __restrict__ fw3L,
    const float* __restrict__ f_b3,
    const float* __restrict__ ts, int step,
    unsigned short* __restrict__ HA2h, unsigned short* __restrict__ HA2l,
    float* __restrict__ drift)
{
    constexpr int BM=64, MI=2;
    __shared__ __align__(16) unsigned short lds[2*(2*BM*64 + 2*128*64)];
    const int bid = blockIdx.x;
    const int lid = (bid & 7)*20 + (bid >> 3);
    const int strip = lid >> 5, rowb = lid & 31;
    const int rowBase = rowb*BM;

    const int tid=threadIdx.x, l=tid&63, wid=tid>>6;
    const int wr=wid>>1, wc=wid&1, r16=l&15, rg=l>>4;

    f32x4 acc[MI][4] = {};
    if (strip < 4) {
        const int colBase = strip*128;
        gemm_core<BM>(lds, ytH, ytL, S_, w1tH, w1tL, S_, rowBase, colBase, acc);
        const float t = ts[3+step];
#pragma unroll
        for (int j=0;j<4;++j){
            int colj = colBase + wc*64 + j*16 + r16;
            float be = g_b1[colj] + t*g_w1[colj];
#pragma unroll
            for (int i=0;i<MI;++i)
#pragma unroll
                for (int reg=0;reg<4;++reg){
                    int row = rowBase + wr*(BM/2) + i*16 + rg*4 + reg;
                    float v = fmaxf(acc[i][j][reg] + be, 0.f);
                    unsigned short h,lo; f2b2(v,h,lo);
                    size_t o = (size_t)row*512 + colj;
                    HA2h[o]=h; HA2l[o]=lo;
                }
        }
    } else {
        gemm_core<BM>(lds, HBh, HBl, H_, fw3H, fw3L, H_, rowBase, 0, acc);
#pragma unroll
        for (int j=0;j<4;++j){
            int colj = wc*64 + j*16 + r16;
            float be = f_b3[colj];
#pragma unroll
            for (int i=0;i<MI;++i)
#pragma unroll
                for (int reg=0;reg<4;++reg){
                    int row = rowBase + wr*(BM/2) + i*16 + rg*4 + reg;
                    drift[row*S_ + colj] = acc[i][j][reg] + be;
                }
        }
    }
}

__global__ __launch_bounds__(256,1) void k4_phase(
    const unsigned short* __restrict__ HA2h, const unsigned short* __restrict__ HA2l,
    const unsigned short* __restrict__ gw2H, const unsigned short* __restrict__ gw2L,
    const float* __restrict__ g_b2,
    const float* __restrict__ y,
    const float* __restrict__ gp,
    const float* __restrict__ drift,
    const float* __restrict__ dWs,
    const float* __restrict__ ts, int step,
    float* __restrict__ y1,
    unsigned short* __restrict__ ycH, unsigned short* __restrict__ ycL)
{
    constexpr int BM=128, MI=4;
    __shared__ __align__(16) unsigned short lds[2*(2*BM*64 + 2*128*64)];
    const int bid = blockIdx.x;
    const int lid = (bid & 7)*32 + (bid >> 3);
    const int strip = lid >> 4, rowb = lid & 15;
    const int rowBase = rowb*BM, colBase = strip*128;

    f32x4 acc[MI][4] = {};
    gemm_core<BM>(lds, HA2h, HA2l, H_, gw2H, gw2L, H_, rowBase, colBase, acc);

    const int tid=threadIdx.x, l=tid&63, wid=tid>>6;
    const int wr=wid>>1, wc=wid&1, r16=l&15, rg=l>>4;
    const float dt = ts[4+step]-ts[3+step], sq = sqrtf(dt);
#pragma unroll
    for (int i=0;i<MI;++i)
#pragma unroll
        for (int reg=0;reg<4;++reg){
            int row = rowBase + wr*(BM/2) + i*16 + rg*4 + reg;
            float dwv = dWs[row*K_ + r16] * sq;
#pragma unroll
            for (int j=0;j<4;++j){
                int colj = colBase + wc*64 + j*16;
                float m = (acc[i][j][reg] + g_b2[colj + r16]) * dwv;
                m += __shfl_xor(m,1); m += __shfl_xor(m,2);
                m += __shfl_xor(m,4); m += __shfl_xor(m,8);
                if (r16 == 0){
                    int idx = row*S_ + (colj>>4);
                    float v1 = y[idx] + drift[idx]*dt + 0.5f*(gp[idx] + m);
                    y1[idx] = v1;
                    unsigned short h,lo; f2b2(v1,h,lo);
                    ycH[idx]=h; ycL[idx]=lo;
                }
            }
        }
}

__global__ __launch_bounds__(256) void tcast_k(
    const float* __restrict__ in, int rowOff, int Kd, int N,
    unsigned short* __restrict__ outH, unsigned short* __restrict__ outL)
{
    __shared__ float tl[32][33];
    const int kb = blockIdx.x*32, nb = blockIdx.y*32;
    const int tx = threadIdx.x, ty = threadIdx.y;
    for (int r = ty; r < 32; r += 8)
        tl[r][tx] = in[(size_t)(rowOff + kb + r)*N + nb + tx];
    __syncthreads();
    for (int r = ty; r < 32; r += 8){
        unsigned short h,lo; f2b2(tl[tx][r],h,lo);
        size_t o = (size_t)(nb + r)*Kd + kb + tx;
        outH[o]=h; outL[o]=lo;
    }
}

__global__ __launch_bounds__(128) void encoder_k(
    const float* __restrict__ x,
    const float* __restrict__ w1, const float* __restrict__ b1,
    const float* __restrict__ w2, const float* __restrict__ b2,
    float* __restrict__ y0,
    unsigned short* __restrict__ ycH, unsigned short* __restrict__ ycL)
{
    int b = blockIdx.x;
    __shared__ float h[H_];
    int tid = threadIdx.x;
    float x0 = x[b*3+0], x1 = x[b*3+1], x2 = x[b*3+2];
    for (int i = tid; i < H_; i += 128)
        h[i] = fmaxf(x0*w1[i] + x1*w1[H_+i] + x2*w1[2*H_+i] + b1[i], 0.f);
    __syncthreads();
    float acc = b2[tid];
    for (int k = 0; k < H_; ++k) acc += h[k]*w2[k*S_+tid];
    size_t o = (size_t)b*S_ + tid;
    y0[o] = acc;
    unsigned short hh,ll; f2b2(acc,hh,ll);
    ycH[o]=hh; ycL[o]=ll;
}

extern "C" void kernel_launch(void* const* d_in, const int* in_sizes, int n_in,
                              void* d_out, int out_size, void* d_ws, size_t ws_size,
                              hipStream_t stream)
{
    const float* ts     = (const float*)d_in[0];
    const float* x      = (const float*)d_in[1];
    const float* enc_w1 = (const float*)d_in[2];
    const float* enc_b1 = (const float*)d_in[3];
    const float* enc_w2 = (const float*)d_in[4];
    const float* enc_b2 = (const float*)d_in[5];
    const float* f_w1   = (const float*)d_in[6];
    const float* f_b1   = (const float*)d_in[7];
    const float* f_w2   = (const float*)d_in[8];
    const float* f_b2   = (const float*)d_in[9];
    const float* f_w3   = (const float*)d_in[10];
    const float* f_b3   = (const float*)d_in[11];
    const float* g_w1   = (const float*)d_in[12];
    const float* g_b1   = (const float*)d_in[13];
    const float* g_w2   = (const float*)d_in[14];
    const float* g_b2   = (const float*)d_in[15];
    const float* dW     = (const float*)d_in[16];

    float* out = (float*)d_out;
    unsigned short* w = (unsigned short*)d_ws;

    unsigned short* w1tH  = w;                      // 1024*128
    unsigned short* w1tL  = w1tH  + 1024*128;
    unsigned short* gw2H  = w1tL  + 1024*128;       // 2048*512
    unsigned short* gw2L  = gw2H  + 2048*512;
    unsigned short* fw2H  = gw2L  + 2048*512;       // 512*512
    unsigned short* fw2L  = fw2H  + 512*512;
    unsigned short* fw3H  = fw2L  + 512*512;        // 128*512
    unsigned short* fw3L  = fw3H  + 128*512;
    unsigned short* HAh   = fw3L  + 128*512;        // 2048*1024
    unsigned short* HAl   = HAh   + 2048*1024;
    unsigned short* HBh   = HAl   + 2048*1024;      // 2048*512
    unsigned short* HBl   = HBh   + 2048*512;
    unsigned short* ytH   = HBl   + 2048*512;       // 2048*128
    unsigned short* ytL   = ytH   + 2048*128;
    unsigned short* ycH   = ytL   + 2048*128;       // 2048*128
    unsigned short* ycL   = ycH   + 2048*128;
    float* gp    = (float*)(ycL + 2048*128);        // 2048*128 f32
    float* drift = gp + 2048*128;                   // 2048*128 f32
    unsigned short* HA2h = HAh;                     // alias (HA dead after K2)
    unsigned short* HA2l = HAl;

    dim3 tb(32,8);
    tcast_k<<<dim3(4,16),  tb, 0, stream>>>(g_w1, 1, 128, 512,  w1tH,          w1tL);
    tcast_k<<<dim3(4,16),  tb, 0, stream>>>(f_w1, 1, 128, 512,  w1tH+512*128,  w1tL+512*128);
    tcast_k<<<dim3(16,16), tb, 0, stream>>>(f_w2, 0, 512, 512,  fw2H,          fw2L);
    tcast_k<<<dim3(16,4),  tb, 0, stream>>>(f_w3, 0, 512, 128,  fw3H,          fw3L);
    tcast_k<<<dim3(16,64), tb, 0, stream>>>(g_w2, 0, 512, 2048, gw2H,          gw2L);

    encoder_k<<<B_, 128, 0, stream>>>(x, enc_w1, enc_b1, enc_w2, enc_b2, out, ycH, ycL);

    for (int step = 0; step < NSTEP; ++step) {
        const float* y   = out + (size_t)step * B_ * S_;
        float*       y1  = out + (size_t)(step+1) * B_ * S_;
        const float* dWs = dW  + (size_t)step * B_ * K_;

        k1_phase<<<256, 256, 0, stream>>>(ycH, ycL, w1tH, w1tL, g_w1, f_w1,
                                          g_b1, f_b1, ts, step, HAh, HAl);
        k2_phase<<<320, 256, 0, stream>>>(HAh, HAl, gw2H, gw2L, fw2H, fw2L,
                                          g_b2, f_b2, y, dWs, ts, step,
                                          gp, ytH, ytL, HBh, HBl);
        k3_phase<<<160, 256, 0, stream>>>(ytH, ytL, w1tH, w1tL, g_b1, g_w1,
                                          HBh, HBl, fw3H, fw3L, f_b3, ts, step,
                                          HA2h, HA2l, drift);
        k4_phase<<<256, 256, 0, stream>>>(HA2h, HA2l, gw2H, gw2L, g_b2,
                                          y, gp, drift, dWs, ts, step,
                                          y1, ycH, ycL);
    }
}